// Round 6
// baseline (302.168 us; speedup 1.0000x reference)
//
#include <hip/hip_runtime.h>
#include <hip/hip_fp16.h>

// Problem constants (match reference)
#define BB      2048
#define CC      1024
#define FF      128
#define NBLK    256
#define RPB     8          // rows per block; also waves per block (TPB=512)
#define TPB     512
#define NITER   10
#define SUBR    8          // colsum accumulator spreading (256/8 = 32-way)
#define KSTRIDE 1028       // Kt row stride: 4112 B, 16B-aligned rows
#define SCALING_F (2048.0f / 100000.0f)

// Cross-block state: accessed ONLY via device-scope atomics (coherence-point
// ops) -> no __threadfence / L2 writeback-invalidate needed anywhere.
__device__ int   g_barCnt;                       // self-resetting (ends at 0)
__device__ int   g_barFlag;                      // sense-reversal (any parity ok)
__device__ float g_meanPart[NBLK];               // atomic store / atomic load
__device__ float g_colsum[NITER * SUBR * CC];    // zeroed in-kernel, atomicAdd

// Fence-free grid barrier: waitcnt orders my prior atomics (acked at the
// coherence point), single counter + sense flag. Replay-safe: counter returns
// to 0, flag parity is read at runtime.
__device__ __forceinline__ void grid_bar() {
    __syncthreads();                 // all waves' atomics issued + waitcnt'd below
    if (threadIdx.x == 0) {
        int sense = __hip_atomic_load(&g_barFlag, __ATOMIC_RELAXED,
                                      __HIP_MEMORY_SCOPE_AGENT);
        asm volatile("s_waitcnt vmcnt(0)" ::: "memory");
        int old = __hip_atomic_fetch_add(&g_barCnt, 1, __ATOMIC_RELAXED,
                                         __HIP_MEMORY_SCOPE_AGENT);
        if (old == NBLK - 1) {
            __hip_atomic_store(&g_barCnt, 0, __ATOMIC_RELAXED,
                               __HIP_MEMORY_SCOPE_AGENT);
            asm volatile("s_waitcnt vmcnt(0)" ::: "memory");  // reset acked first
            __hip_atomic_store(&g_barFlag, sense ^ 1, __ATOMIC_RELAXED,
                               __HIP_MEMORY_SCOPE_AGENT);
        } else {
            while (__hip_atomic_load(&g_barFlag, __ATOMIC_RELAXED,
                                     __HIP_MEMORY_SCOPE_AGENT) == sense)
                __builtin_amdgcn_s_sleep(1);
        }
    }
    __syncthreads();
}

// Each wave's atomics must be acked before its thread reaches grid_bar's
// __syncthreads; issue this in every thread right after its atomicAdds.
#define WAIT_MY_ATOMICS() asm volatile("s_waitcnt vmcnt(0)" ::: "memory")

// LDS: Kt 32896 + dott 16384 + uesh 4096 + vsh 4096 + capsh 4096 + misc
//      = ~61.6 KB (< 64 KB static)
__global__ void __launch_bounds__(TPB)
sink_all(const int* __restrict__ users, const int* __restrict__ items,
         const float* __restrict__ D, const float* __restrict__ caps,
         const float* __restrict__ iemb, const float* __restrict__ uemb,
         float* __restrict__ out)
{
    const int bid = blockIdx.x, tid = threadIdx.x;
    const int r0 = bid * RPB;
    const int w = tid >> 6, l = tid & 63;

    __shared__ __align__(16) float  Kt[RPB][KSTRIDE];
    __shared__ __align__(16) __half dott[RPB][CC];
    __shared__ __align__(16) float  uesh[RPB][FF];
    __shared__ __align__(16) float  vsh[CC];
    __shared__ __align__(16) float  capsh[CC];
    __shared__ float ush[RPB];
    __shared__ float red[RPB];

    // ---- A: zero my colsum slice (atomic stores: coherent with atomicAdds),
    //         D tile -> Kt (+ mean partial), uesh, capsh, dot GEMM ----------
    if (tid < (NITER * SUBR * CC) / NBLK)    // 320 floats per block
        __hip_atomic_store(&g_colsum[bid * 320 + tid], 0.0f,
                           __ATOMIC_RELAXED, __HIP_MEMORY_SCOPE_AGENT);

    float psum = 0.0f;
    {
        const float4* D4 = (const float4*)(D + ((size_t)r0 << 10));
        for (int i = tid; i < RPB * CC / 4; i += TPB) {
            float4 d = D4[i];
            int r = i >> 8, c4 = (i & 255) << 2;
            *(float4*)&Kt[r][c4] = d;
            psum += d.x + d.y + d.z + d.w;
        }
    }
    if (tid < 256) {                         // stage 8 user embeddings
        int r = tid >> 5, f4 = tid & 31;
        int u = users[r0 + r];
        ((float4*)uesh[r])[f4] = ((const float4*)(uemb + (size_t)u * FF))[f4];
    }
    for (int c = tid; c < CC; c += TPB) capsh[c] = caps[c] * SCALING_F;
    {
        float p = psum;
        #pragma unroll
        for (int off = 32; off > 0; off >>= 1) p += __shfl_xor(p, off, 64);
        if (l == 0) red[w] = p;
    }
    __syncthreads();                         // uesh + red ready
    if (tid == 0) {
        float s = 0.0f;
        #pragma unroll
        for (int k = 0; k < RPB; ++k) s += red[k];
        __hip_atomic_store(&g_meanPart[bid], s,
                           __ATOMIC_RELAXED, __HIP_MEMORY_SCOPE_AGENT);
    }

    // dot GEMM: dott[r][j] = uesh[r] . iemb[j]; j in {tid, tid+512}.
    // 8 LDS b-reads per f4 shared across both j's (broadcast, conflict-free).
    {
        float acc0[RPB] = {}, acc1[RPB] = {};
        const float4* ip0 = (const float4*)(iemb + (size_t)tid * FF);
        const float4* ip1 = (const float4*)(iemb + (size_t)(tid + TPB) * FF);
        for (int f4 = 0; f4 < FF / 4; ++f4) {
            float4 a0 = ip0[f4], a1 = ip1[f4];
            #pragma unroll
            for (int r = 0; r < RPB; ++r) {
                float4 b = ((const float4*)uesh[r])[f4];
                acc0[r] += a0.x * b.x + a0.y * b.y + a0.z * b.z + a0.w * b.w;
                acc1[r] += a1.x * b.x + a1.y * b.y + a1.z * b.z + a1.w * b.w;
            }
        }
        #pragma unroll
        for (int r = 0; r < RPB; ++r) {
            dott[r][tid]       = __float2half(acc0[r]);
            dott[r][tid + TPB] = __float2half(acc1[r]);
        }
    }

    WAIT_MY_ATOMICS();
    grid_bar();                              // BAR1: meanPart + colsum zeros

    // ---- B: s2 = 5*B*C/sum(D); K = exp(5*dot - s2*D) in place in Kt -------
    if (tid < 256) {
        float v = __hip_atomic_load(&g_meanPart[tid], __ATOMIC_RELAXED,
                                    __HIP_MEMORY_SCOPE_AGENT);
        #pragma unroll
        for (int off = 32; off > 0; off >>= 1) v += __shfl_xor(v, off, 64);
        if (l == 0) red[w] = v;              // waves 0..3
    }
    __syncthreads();
    const float s2 = 5.0f * (float)(BB * CC) / (red[0] + red[1] + red[2] + red[3]);
    {
        const int4* it4 = (const int4*)(items + ((size_t)r0 << 10));
        for (int i = tid; i < RPB * CC / 4; i += TPB) {
            int4 iv = it4[i];
            int r = i >> 8, c4 = (i & 255) << 2;
            float4 d = *(float4*)&Kt[r][c4];
            float4 kv;
            kv.x = __expf(5.0f * __half2float(dott[r][iv.x]) - s2 * d.x);
            kv.y = __expf(5.0f * __half2float(dott[r][iv.y]) - s2 * d.y);
            kv.z = __expf(5.0f * __half2float(dott[r][iv.z]) - s2 * d.z);
            kv.w = __expf(5.0f * __half2float(dott[r][iv.w]) - s2 * d.w);
            *(float4*)&Kt[r][c4] = kv;
        }
    }
    __syncthreads();

    // ---- C: 10 Sinkhorn iterations, one fence-free grid barrier each ------
    for (int t = 0; t < NITER; ++t) {
        if (t == 0) {
            for (int c = tid; c < CC; c += TPB) vsh[c] = 1.0f;
        } else {
            const float* base = g_colsum + (size_t)(t - 1) * SUBR * CC;
            for (int c = tid; c < CC; c += TPB) {
                float s = 0.0f;
                #pragma unroll
                for (int k = 0; k < SUBR; ++k)
                    s += __hip_atomic_load(&base[k * CC + c], __ATOMIC_RELAXED,
                                           __HIP_MEMORY_SCOPE_AGENT);
                vsh[c] = capsh[c] / s;
            }
        }
        __syncthreads();
        // u_w = 1/(K v)_w : wave w owns row w (LDS float4, conflict-free)
        {
            const float4* kr = (const float4*)Kt[w];
            const float4* v4 = (const float4*)vsh;
            float p = 0.0f;
            #pragma unroll
            for (int j = 0; j < 4; ++j) {
                float4 k = kr[l + 64 * j], v = v4[l + 64 * j];
                p += k.x * v.x + k.y * v.y + k.z * v.z + k.w * v.w;
            }
            #pragma unroll
            for (int off = 32; off > 0; off >>= 1) p += __shfl_xor(p, off, 64);
            if (l == 0) ush[w] = 1.0f / p;
        }
        __syncthreads();
        // colsum partials: thread owns col pair 2*tid (coalesced LDS rows)
        {
            float sx = 0.0f, sy = 0.0f;
            #pragma unroll
            for (int r = 0; r < RPB; ++r) {
                float2 k = *(const float2*)&Kt[r][2 * tid];
                float ur = ush[r];
                sx += k.x * ur; sy += k.y * ur;
            }
            float* cb = g_colsum + ((size_t)t * SUBR + (bid & (SUBR - 1))) * CC
                      + 2 * tid;
            atomicAdd(cb, sx);
            atomicAdd(cb + 1, sy);
        }
        WAIT_MY_ATOMICS();
        grid_bar();
    }

    // ---- D: v10 from colsum[9]; u10 = ush (from iter 9); P = K*u(x)v ------
    {
        const float* base = g_colsum + (size_t)(NITER - 1) * SUBR * CC;
        for (int c = tid; c < CC; c += TPB) {
            float s = 0.0f;
            #pragma unroll
            for (int k = 0; k < SUBR; ++k)
                s += __hip_atomic_load(&base[k * CC + c], __ATOMIC_RELAXED,
                                       __HIP_MEMORY_SCOPE_AGENT);
            vsh[c] = capsh[c] / s;
        }
        __syncthreads();
        const float4* kr = (const float4*)Kt[w];
        const float4* v4 = (const float4*)vsh;
        const float u = ush[w];
        float4* o4 = (float4*)(out + ((size_t)(r0 + w) << 10));
        #pragma unroll
        for (int j = 0; j < 4; ++j) {
            float4 k = kr[l + 64 * j], v = v4[l + 64 * j];
            float4 p;
            p.x = k.x * u * v.x;  p.y = k.y * u * v.y;
            p.z = k.z * u * v.z;  p.w = k.w * u * v.w;
            o4[l + 64 * j] = p;
        }
    }
}

extern "C" void kernel_launch(void* const* d_in, const int* in_sizes, int n_in,
                              void* d_out, int out_size, void* d_ws, size_t ws_size,
                              hipStream_t stream) {
    const int*   users = (const int*)d_in[0];
    const int*   items = (const int*)d_in[1];
    const float* D     = (const float*)d_in[2];
    const float* caps  = (const float*)d_in[3];
    const float* iemb  = (const float*)d_in[4];
    const float* uemb  = (const float*)d_in[5];
    float* out = (float*)d_out;

    void* args[] = { (void*)&users, (void*)&items, (void*)&D, (void*)&caps,
                     (void*)&iemb, (void*)&uemb, (void*)&out };
    hipLaunchCooperativeKernel((void*)sink_all, dim3(NBLK), dim3(TPB),
                               args, 0, stream);
}

// Round 7
// 233.008 us; speedup vs baseline: 1.2968x; 1.2968x over previous
//
#include <hip/hip_runtime.h>
#include <hip/hip_fp16.h>

// Problem constants (match reference)
#define BB      2048
#define CC      1024
#define FF      128
#define NBLK    256
#define RPB     8          // rows per block; also waves per block (TPB=512)
#define TPB     512
#define NITER   10
#define SUBR    8          // colsum accumulator spreading (256/8 = 32-way)
#define KSTRIDE 1028       // Kt row stride: 4112 B, 16B-aligned rows
#define LINE    32         // ints per 128 B cache line
#define SCALING_F (2048.0f / 100000.0f)

// Cross-block state: accessed ONLY via device-scope atomics (coherence-point
// ops) -> no __threadfence / L2 writeback-invalidate needed anywhere.
// Barrier state is monotonic (never reset) -> graph-replay safe via the F0
// snapshot; each array sits on its own 128 B line so arrive-RMW traffic and
// poll-load traffic never collide on a line.
__device__ int   g_leafCnt[8 * LINE];            // 8 leaf counters, 128 B apart
__device__ int   g_rootCnt[LINE];                // root counter, own line
__device__ int   g_flag[LINE];                   // completion flag, own line
__device__ float g_meanPart[NBLK];               // atomic store / atomic load
__device__ float g_colsum[NITER * SUBR * CC];    // zeroed in-kernel, atomicAdd

// Fence-free two-level grid barrier. Thread 0 only; roundAbs is absolute
// (F0 + local round). Pollers read the flag line only (no RMW interference).
__device__ __forceinline__ void grid_bar(int bid, int roundAbs) {
    __syncthreads();
    if (threadIdx.x == 0) {
        asm volatile("s_waitcnt vmcnt(0)" ::: "memory");  // my atomics acked
        int old = __hip_atomic_fetch_add(&g_leafCnt[(bid & 7) * LINE], 1,
                                         __ATOMIC_RELAXED, __HIP_MEMORY_SCOPE_AGENT);
        if (old + 1 == 32 * roundAbs) {                   // leaf-last (32/leaf)
            int oldr = __hip_atomic_fetch_add(&g_rootCnt[0], 1,
                                              __ATOMIC_RELAXED, __HIP_MEMORY_SCOPE_AGENT);
            if (oldr + 1 == 8 * roundAbs) {               // root-last
                asm volatile("s_waitcnt vmcnt(0)" ::: "memory");
                __hip_atomic_store(&g_flag[0], roundAbs,
                                   __ATOMIC_RELAXED, __HIP_MEMORY_SCOPE_AGENT);
            }
        }
        while (__hip_atomic_load(&g_flag[0], __ATOMIC_RELAXED,
                                 __HIP_MEMORY_SCOPE_AGENT) < roundAbs)
            __builtin_amdgcn_s_sleep(4);
    }
    __syncthreads();
}

// Each wave's atomicAdds must be acked before its threads enter grid_bar.
#define WAIT_MY_ATOMICS() asm volatile("s_waitcnt vmcnt(0)" ::: "memory")

// LDS: Kt 32896 + dott 16384 + uesh 4096 + vsh 4096 + capsh 4096 + misc
//      = ~61.6 KB (< 64 KB static)
__global__ void __launch_bounds__(TPB)
sink_all(const int* __restrict__ users, const int* __restrict__ items,
         const float* __restrict__ D, const float* __restrict__ caps,
         const float* __restrict__ iemb, const float* __restrict__ uemb,
         float* __restrict__ out)
{
    const int bid = blockIdx.x, tid = threadIdx.x;
    const int r0 = bid * RPB;
    const int w = tid >> 6, l = tid & 63;

    __shared__ __align__(16) float  Kt[RPB][KSTRIDE];
    __shared__ __align__(16) __half dott[RPB][CC];
    __shared__ __align__(16) float  uesh[RPB][FF];
    __shared__ __align__(16) float  vsh[CC];
    __shared__ __align__(16) float  capsh[CC];
    __shared__ float ush[RPB];
    __shared__ float red[RPB];

    // F0 snapshot: settled flag value from the previous launch (0 after load).
    // Only thread 0 consumes it; barrier rounds are F0+1, F0+2, ...
    int roundAbs = 0;
    if (tid == 0)
        roundAbs = __hip_atomic_load(&g_flag[0], __ATOMIC_RELAXED,
                                     __HIP_MEMORY_SCOPE_AGENT);

    // ---- A: zero my colsum slice (atomic stores: coherent with atomicAdds),
    //         D tile -> Kt (+ mean partial), uesh, capsh, dot GEMM ----------
    if (tid < (NITER * SUBR * CC) / NBLK)    // 320 floats per block
        __hip_atomic_store(&g_colsum[bid * 320 + tid], 0.0f,
                           __ATOMIC_RELAXED, __HIP_MEMORY_SCOPE_AGENT);

    float psum = 0.0f;
    {
        const float4* D4 = (const float4*)(D + ((size_t)r0 << 10));
        for (int i = tid; i < RPB * CC / 4; i += TPB) {
            float4 d = D4[i];
            int r = i >> 8, c4 = (i & 255) << 2;
            *(float4*)&Kt[r][c4] = d;
            psum += d.x + d.y + d.z + d.w;
        }
    }
    if (tid < 256) {                         // stage 8 user embeddings
        int r = tid >> 5, f4 = tid & 31;
        int u = users[r0 + r];
        ((float4*)uesh[r])[f4] = ((const float4*)(uemb + (size_t)u * FF))[f4];
    }
    for (int c = tid; c < CC; c += TPB) capsh[c] = caps[c] * SCALING_F;
    {
        float p = psum;
        #pragma unroll
        for (int off = 32; off > 0; off >>= 1) p += __shfl_xor(p, off, 64);
        if (l == 0) red[w] = p;
    }
    __syncthreads();                         // uesh + red ready
    if (tid == 0) {
        float s = 0.0f;
        #pragma unroll
        for (int k = 0; k < RPB; ++k) s += red[k];
        __hip_atomic_store(&g_meanPart[bid], s,
                           __ATOMIC_RELAXED, __HIP_MEMORY_SCOPE_AGENT);
    }

    // dot GEMM: dott[r][j] = uesh[r] . iemb[j]; j in {tid, tid+512}.
    {
        float acc0[RPB] = {}, acc1[RPB] = {};
        const float4* ip0 = (const float4*)(iemb + (size_t)tid * FF);
        const float4* ip1 = (const float4*)(iemb + (size_t)(tid + TPB) * FF);
        for (int f4 = 0; f4 < FF / 4; ++f4) {
            float4 a0 = ip0[f4], a1 = ip1[f4];
            #pragma unroll
            for (int r = 0; r < RPB; ++r) {
                float4 b = ((const float4*)uesh[r])[f4];
                acc0[r] += a0.x * b.x + a0.y * b.y + a0.z * b.z + a0.w * b.w;
                acc1[r] += a1.x * b.x + a1.y * b.y + a1.z * b.z + a1.w * b.w;
            }
        }
        #pragma unroll
        for (int r = 0; r < RPB; ++r) {
            dott[r][tid]       = __float2half(acc0[r]);
            dott[r][tid + TPB] = __float2half(acc1[r]);
        }
    }

    WAIT_MY_ATOMICS();
    ++roundAbs; grid_bar(bid, roundAbs);     // BAR1: meanPart + colsum zeros

    // ---- B: s2 = 5*B*C/sum(D); K = exp(5*dot - s2*D) in place in Kt -------
    if (tid < 256) {
        float v = __hip_atomic_load(&g_meanPart[tid], __ATOMIC_RELAXED,
                                    __HIP_MEMORY_SCOPE_AGENT);
        #pragma unroll
        for (int off = 32; off > 0; off >>= 1) v += __shfl_xor(v, off, 64);
        if (l == 0) red[w] = v;              // waves 0..3
    }
    __syncthreads();
    const float s2 = 5.0f * (float)(BB * CC) / (red[0] + red[1] + red[2] + red[3]);
    {
        const int4* it4 = (const int4*)(items + ((size_t)r0 << 10));
        for (int i = tid; i < RPB * CC / 4; i += TPB) {
            int4 iv = it4[i];
            int r = i >> 8, c4 = (i & 255) << 2;
            float4 d = *(float4*)&Kt[r][c4];
            float4 kv;
            kv.x = __expf(5.0f * __half2float(dott[r][iv.x]) - s2 * d.x);
            kv.y = __expf(5.0f * __half2float(dott[r][iv.y]) - s2 * d.y);
            kv.z = __expf(5.0f * __half2float(dott[r][iv.z]) - s2 * d.z);
            kv.w = __expf(5.0f * __half2float(dott[r][iv.w]) - s2 * d.w);
            *(float4*)&Kt[r][c4] = kv;
        }
    }
    __syncthreads();

    // ---- C: 10 Sinkhorn iterations, one fence-free grid barrier each ------
    for (int t = 0; t < NITER; ++t) {
        if (t == 0) {
            for (int c = tid; c < CC; c += TPB) vsh[c] = 1.0f;
        } else {
            const float* base = g_colsum + (size_t)(t - 1) * SUBR * CC;
            for (int c = tid; c < CC; c += TPB) {
                float s = 0.0f;
                #pragma unroll
                for (int k = 0; k < SUBR; ++k)
                    s += __hip_atomic_load(&base[k * CC + c], __ATOMIC_RELAXED,
                                           __HIP_MEMORY_SCOPE_AGENT);
                vsh[c] = capsh[c] / s;
            }
        }
        __syncthreads();
        // u_w = 1/(K v)_w : wave w owns row w (LDS float4, conflict-free)
        {
            const float4* kr = (const float4*)Kt[w];
            const float4* v4 = (const float4*)vsh;
            float p = 0.0f;
            #pragma unroll
            for (int j = 0; j < 4; ++j) {
                float4 k = kr[l + 64 * j], v = v4[l + 64 * j];
                p += k.x * v.x + k.y * v.y + k.z * v.z + k.w * v.w;
            }
            #pragma unroll
            for (int off = 32; off > 0; off >>= 1) p += __shfl_xor(p, off, 64);
            if (l == 0) ush[w] = 1.0f / p;
        }
        __syncthreads();
        // colsum partials: thread owns col pair 2*tid (coalesced LDS rows)
        {
            float sx = 0.0f, sy = 0.0f;
            #pragma unroll
            for (int r = 0; r < RPB; ++r) {
                float2 k = *(const float2*)&Kt[r][2 * tid];
                float ur = ush[r];
                sx += k.x * ur; sy += k.y * ur;
            }
            float* cb = g_colsum + ((size_t)t * SUBR + (bid & (SUBR - 1))) * CC
                      + 2 * tid;
            atomicAdd(cb, sx);
            atomicAdd(cb + 1, sy);
        }
        WAIT_MY_ATOMICS();
        ++roundAbs; grid_bar(bid, roundAbs);
    }

    // ---- D: v10 from colsum[9]; u10 = ush (from iter 9); P = K*u(x)v ------
    {
        const float* base = g_colsum + (size_t)(NITER - 1) * SUBR * CC;
        for (int c = tid; c < CC; c += TPB) {
            float s = 0.0f;
            #pragma unroll
            for (int k = 0; k < SUBR; ++k)
                s += __hip_atomic_load(&base[k * CC + c], __ATOMIC_RELAXED,
                                       __HIP_MEMORY_SCOPE_AGENT);
            vsh[c] = capsh[c] / s;
        }
        __syncthreads();
        const float4* kr = (const float4*)Kt[w];
        const float4* v4 = (const float4*)vsh;
        const float u = ush[w];
        float4* o4 = (float4*)(out + ((size_t)(r0 + w) << 10));
        #pragma unroll
        for (int j = 0; j < 4; ++j) {
            float4 k = kr[l + 64 * j], v = v4[l + 64 * j];
            float4 p;
            p.x = k.x * u * v.x;  p.y = k.y * u * v.y;
            p.z = k.z * u * v.z;  p.w = k.w * u * v.w;
            o4[l + 64 * j] = p;
        }
    }
}

extern "C" void kernel_launch(void* const* d_in, const int* in_sizes, int n_in,
                              void* d_out, int out_size, void* d_ws, size_t ws_size,
                              hipStream_t stream) {
    const int*   users = (const int*)d_in[0];
    const int*   items = (const int*)d_in[1];
    const float* D     = (const float*)d_in[2];
    const float* caps  = (const float*)d_in[3];
    const float* iemb  = (const float*)d_in[4];
    const float* uemb  = (const float*)d_in[5];
    float* out = (float*)d_out;

    void* args[] = { (void*)&users, (void*)&items, (void*)&D, (void*)&caps,
                     (void*)&iemb, (void*)&uemb, (void*)&out };
    hipLaunchCooperativeKernel((void*)sink_all, dim3(NBLK), dim3(TPB),
                               args, 0, stream);
}

// Round 8
// 207.647 us; speedup vs baseline: 1.4552x; 1.1221x over previous
//
#include <hip/hip_runtime.h>
#include <hip/hip_fp16.h>

// Problem constants (match reference)
#define BB      2048
#define CC      1024
#define FF      128
#define NBLK    256
#define RPB     8        // rows per block (NBLK*RPB == BB); waves per block
#define TPB     512
#define NITER   10
#define SUBR    8        // colsum accumulator spreading (256/8 = 32-way)
#define LINE    32       // ints/floats per 128 B cache line
#define CSLICE  ((NITER * SUBR * CC) / NBLK)   // 320 colsum floats per block
#define SCALING_F (2048.0f / 100000.0f)

// Static device storage (graph-capture-safe, fully rewritten per call).
// g_cnt is MONOTONIC (never reset): replay-safe via F0 capture.
__device__ int   g_cnt[8 * LINE];           // arrival leaves, 128 B apart
__device__ float g_meanPart[NBLK * LINE];   // slot b at b*LINE (own line)
__device__ float g_K[BB * CC];              // 8 MB fp32 K
__device__ float g_colsum[NITER * SUBR * CC];
__device__ float g_u[BB];                   // u published by k_iter t=9

// ---- K1: mean(D) reduction + dot GEMM + exp -> K (merged former k0) --------
__global__ void __launch_bounds__(TPB)
k1_buildK(const int* __restrict__ users, const int* __restrict__ items,
          const float* __restrict__ D, const float* __restrict__ iemb,
          const float* __restrict__ uemb) {
    const int bid = blockIdx.x, tid = threadIdx.x;
    const int r0 = bid * RPB;
    const int w = tid >> 6, l = tid & 63;

    __shared__ __align__(16) float  Dsh[RPB][CC];    // 32 KB
    __shared__ __align__(16) __half dott[RPB][CC];   // 16 KB
    __shared__ __align__(16) float  uesh[RPB][FF];   // 4 KB
    __shared__ float red[RPB];
    __shared__ float s2sh;

    // F0: settled arrival count BEFORE this block's own add -> spin target.
    // (sum < 256*(n+1) is guaranteed while my add is missing, so floor is n.)
    int target = 0;
    if (w == 0) {
        int c = (l < 8) ? __hip_atomic_load(&g_cnt[l * LINE], __ATOMIC_RELAXED,
                                            __HIP_MEMORY_SCOPE_AGENT) : 0;
        #pragma unroll
        for (int off = 32; off > 0; off >>= 1) c += __shfl_xor(c, off, 64);
        target = (c / NBLK + 1) * NBLK;
    }

    // zero my colsum slice (normal stores; kernel boundary flushes them)
    if (tid < CSLICE) g_colsum[bid * CSLICE + tid] = 0.0f;

    // D slice -> LDS + block partial sum
    float psum = 0.0f;
    {
        const float4* D4 = (const float4*)(D + ((size_t)r0 << 10));
        for (int i = tid; i < RPB * CC / 4; i += TPB) {
            float4 d = D4[i];
            int r = i >> 8, c4 = (i & 255) << 2;
            *(float4*)&Dsh[r][c4] = d;
            psum += d.x + d.y + d.z + d.w;
        }
        #pragma unroll
        for (int off = 32; off > 0; off >>= 1) psum += __shfl_xor(psum, off, 64);
        if (l == 0) red[w] = psum;
    }
    if (tid < 256) {                        // stage 8 user embeddings
        int r = tid >> 5, f4 = tid & 31;
        int u = users[r0 + r];
        ((float4*)uesh[r])[f4] = ((const float4*)(uemb + (size_t)u * FF))[f4];
    }
    __syncthreads();
    if (tid == 0) {                         // publish partial, then arrive
        float s = 0.0f;
        #pragma unroll
        for (int k = 0; k < RPB; ++k) s += red[k];
        __hip_atomic_store(&g_meanPart[bid * LINE], s,
                           __ATOMIC_RELAXED, __HIP_MEMORY_SCOPE_AGENT);
        asm volatile("s_waitcnt vmcnt(0)" ::: "memory");   // partial acked
        __hip_atomic_fetch_add(&g_cnt[(bid & 7) * LINE], 1,
                               __ATOMIC_RELAXED, __HIP_MEMORY_SCOPE_AGENT);
    }

    // dot GEMM (overlaps the global mean reduction): dott[r][j], j=tid,tid+512
    {
        float acc0[RPB] = {}, acc1[RPB] = {};
        const float4* ip0 = (const float4*)(iemb + (size_t)tid * FF);
        const float4* ip1 = (const float4*)(iemb + (size_t)(tid + TPB) * FF);
        for (int f4 = 0; f4 < FF / 4; ++f4) {
            float4 a0 = ip0[f4], a1 = ip1[f4];
            #pragma unroll
            for (int r = 0; r < RPB; ++r) {
                float4 b = ((const float4*)uesh[r])[f4];   // broadcast LDS
                acc0[r] += a0.x * b.x + a0.y * b.y + a0.z * b.z + a0.w * b.w;
                acc1[r] += a1.x * b.x + a1.y * b.y + a1.z * b.z + a1.w * b.w;
            }
        }
        #pragma unroll
        for (int r = 0; r < RPB; ++r) {
            dott[r][tid]       = __float2half(acc0[r]);
            dott[r][tid + TPB] = __float2half(acc1[r]);
        }
    }
    __syncthreads();

    // mean spin (settled during the GEMM; usually zero iterations) + s2
    if (w == 0) {
        for (;;) {
            int c = (l < 8) ? __hip_atomic_load(&g_cnt[l * LINE], __ATOMIC_RELAXED,
                                                __HIP_MEMORY_SCOPE_AGENT) : 0;
            #pragma unroll
            for (int off = 32; off > 0; off >>= 1) c += __shfl_xor(c, off, 64);
            if (c >= target) break;
            __builtin_amdgcn_s_sleep(4);
        }
        float m = 0.0f;
        #pragma unroll
        for (int k = 0; k < 4; ++k)
            m += __hip_atomic_load(&g_meanPart[(l + 64 * k) * LINE],
                                   __ATOMIC_RELAXED, __HIP_MEMORY_SCOPE_AGENT);
        #pragma unroll
        for (int off = 32; off > 0; off >>= 1) m += __shfl_xor(m, off, 64);
        if (l == 0) s2sh = 5.0f * (float)(BB * CC) / m;
    }
    __syncthreads();

    // K = exp(5*dot - s2*D) -> g_K (normal float4 stores)
    const float s2 = s2sh;
    const int4* it4 = (const int4*)(items + ((size_t)r0 << 10));
    float4*     K4  = (float4*)(g_K + ((size_t)r0 << 10));
    for (int i = tid; i < RPB * CC / 4; i += TPB) {
        int4 iv = it4[i];
        int r = i >> 8, c4 = (i & 255) << 2;
        float4 d = *(float4*)&Dsh[r][c4];
        float4 kv;
        kv.x = __expf(5.0f * __half2float(dott[r][iv.x]) - s2 * d.x);
        kv.y = __expf(5.0f * __half2float(dott[r][iv.y]) - s2 * d.y);
        kv.z = __expf(5.0f * __half2float(dott[r][iv.z]) - s2 * d.z);
        kv.w = __expf(5.0f * __half2float(dott[r][iv.w]) - s2 * d.w);
        K4[i] = kv;
    }
}

// ---- K_iter(t): v_t -> u = 1/(K v_t) -> colsum[t] += K^T u ------------------
// Wave w owns row r0+w; K row loaded once into regs (issued before v-phase),
// stashed to LDS for the colsum phase. t==9 publishes u for k_final.
__global__ void __launch_bounds__(TPB)
k_iter(const float* __restrict__ caps, int t) {
    const int bid = blockIdx.x, tid = threadIdx.x;
    const int r0 = bid * RPB;
    const int w = tid >> 6, l = tid & 63;

    __shared__ __align__(16) float Kt[RPB][CC];   // 32 KB
    __shared__ __align__(16) float vsh[CC];
    __shared__ float ush[RPB];

    const float4* kr = (const float4*)(g_K + ((size_t)(r0 + w) << 10));
    float4 k4[4];
    #pragma unroll
    for (int j = 0; j < 4; ++j) k4[j] = kr[l + 64 * j];   // in flight

    for (int c = tid; c < CC; c += TPB) {
        float v = 1.0f;
        if (t > 0) {
            const float* base = g_colsum + (size_t)(t - 1) * SUBR * CC;
            float s = 0.0f;
            #pragma unroll
            for (int k = 0; k < SUBR; ++k) s += base[k * CC + c];
            v = caps[c] * SCALING_F / s;
        }
        vsh[c] = v;
    }
    __syncthreads();

    {
        const float4* v4 = (const float4*)vsh;
        float4* KtF4 = (float4*)Kt[w];
        float p = 0.0f;
        #pragma unroll
        for (int j = 0; j < 4; ++j) {
            float4 v = v4[l + 64 * j];
            p += k4[j].x * v.x + k4[j].y * v.y + k4[j].z * v.z + k4[j].w * v.w;
            KtF4[l + 64 * j] = k4[j];
        }
        #pragma unroll
        for (int off = 32; off > 0; off >>= 1) p += __shfl_xor(p, off, 64);
        if (l == 0) {
            float u = 1.0f / p;
            ush[w] = u;
            if (t == NITER - 1) g_u[r0 + w] = u;   // boundary-flushed
        }
    }
    __syncthreads();

    {
        float sx = 0.0f, sy = 0.0f;
        #pragma unroll
        for (int r = 0; r < RPB; ++r) {
            float2 k = *(const float2*)&Kt[r][2 * tid];
            float ur = ush[r];
            sx += k.x * ur; sy += k.y * ur;
        }
        float* cb = g_colsum + ((size_t)t * SUBR + (bid & (SUBR - 1))) * CC
                  + 2 * tid;
        atomicAdd(cb, sx);
        atomicAdd(cb + 1, sy);
    }
}

// ---- K_final: u from g_u, v10 from colsum[9], P = K * u (x) v ---------------
__global__ void __launch_bounds__(TPB)
k_final(const float* __restrict__ caps, float* __restrict__ out) {
    const int bid = blockIdx.x, tid = threadIdx.x;
    const int r0 = bid * RPB;
    const int w = tid >> 6, l = tid & 63;

    __shared__ __align__(16) float vsh[CC];

    const float u = g_u[r0 + w];                  // wave-uniform scalar load
    const float4* kr = (const float4*)(g_K + ((size_t)(r0 + w) << 10));
    float4 k4[4];
    #pragma unroll
    for (int j = 0; j < 4; ++j) k4[j] = kr[l + 64 * j];   // in flight

    {
        const float* base = g_colsum + (size_t)(NITER - 1) * SUBR * CC;
        for (int c = tid; c < CC; c += TPB) {
            float s = 0.0f;
            #pragma unroll
            for (int k = 0; k < SUBR; ++k) s += base[k * CC + c];
            vsh[c] = caps[c] * SCALING_F / s;
        }
    }
    __syncthreads();

    {
        const float4* v4 = (const float4*)vsh;
        float4* o4 = (float4*)(out + ((size_t)(r0 + w) << 10));
        #pragma unroll
        for (int j = 0; j < 4; ++j) {
            float4 v = v4[l + 64 * j];
            float4 p;
            p.x = k4[j].x * u * v.x;  p.y = k4[j].y * u * v.y;
            p.z = k4[j].z * u * v.z;  p.w = k4[j].w * u * v.w;
            o4[l + 64 * j] = p;
        }
    }
}

extern "C" void kernel_launch(void* const* d_in, const int* in_sizes, int n_in,
                              void* d_out, int out_size, void* d_ws, size_t ws_size,
                              hipStream_t stream) {
    const int*   users = (const int*)d_in[0];
    const int*   items = (const int*)d_in[1];
    const float* D     = (const float*)d_in[2];
    const float* caps  = (const float*)d_in[3];
    const float* iemb  = (const float*)d_in[4];
    const float* uemb  = (const float*)d_in[5];
    float* out = (float*)d_out;

    hipLaunchKernelGGL(k1_buildK, dim3(NBLK), dim3(TPB), 0, stream,
                       users, items, D, iemb, uemb);
    for (int t = 0; t < NITER; ++t)
        hipLaunchKernelGGL(k_iter, dim3(NBLK), dim3(TPB), 0, stream, caps, t);
    hipLaunchKernelGGL(k_final, dim3(NBLK), dim3(TPB), 0, stream, caps, out);
}